// Round 9
// baseline (35893.289 us; speedup 1.0000x reference)
//
#include <hip/hip_runtime.h>

// ===========================================================================
// GAT_CNN_DASE :: gfx950 :: R9.  KEY FIX: d_out is FLOAT32 (proved by R4-R8
// bit-identical error = labels-as-f32 artifact 0x3F803F80=1.0019 vs ref 0.031).
// All outputs written as f32. Inputs dtype-sniffed per array (bf16 vs f32)
// and canonicalized: front-end -> f32 (cnn accuracy), MLP -> bf16.
// VALU GEMMs (correctness round); MFMA returns next round.
// ===========================================================================

typedef unsigned short u16;

__device__ __forceinline__ float b2f(u16 u) {
  unsigned v = ((unsigned)u) << 16;
  return __builtin_bit_cast(float, v);
}
__device__ __forceinline__ u16 f2b(float f) {
  unsigned x = __builtin_bit_cast(unsigned, f);
  x += 0x7fffu + ((x >> 16) & 1u);
  return (u16)(x >> 16);
}

// bf16 data: ~100% of u16s have exponent in [100,140]; f32-as-u16: ~58%.
__device__ __forceinline__ int sniff_bf16(const void* p, int n) {
  const u16* pu = (const u16*)p;
  int ns = n < 128 ? n : 128;
  int sane = 0, nz = 0;
  for (int i = 0; i < ns; i++) {
    u16 v = pu[i];
    if (v) nz++;
    int e = (v >> 7) & 0xFF;
    if (e >= 100 && e <= 140) sane++;
  }
  return (nz == 0) || (sane * 8 >= ns * 7);
}
__device__ __forceinline__ float ld_any(const void* p, int i, int isbf) {
  return isbf ? b2f(((const u16*)p)[i]) : ((const float*)p)[i];
}

__global__ void cvt_f(const void* __restrict__ in, float* __restrict__ out,
                      int n) {
  __shared__ int sbf;
  if (threadIdx.x == 0) sbf = sniff_bf16(in, n);
  __syncthreads();
  int tid = blockIdx.x * 256 + threadIdx.x;
  if (tid < n) out[tid] = ld_any(in, tid, sbf);
}
// in[k*N+n] -> out[n*K+k]
__global__ void cvt_f_t(const void* __restrict__ in, float* __restrict__ out,
                        int K, int N) {
  __shared__ int sbf;
  if (threadIdx.x == 0) sbf = sniff_bf16(in, K * N);
  __syncthreads();
  int tid = blockIdx.x * 256 + threadIdx.x;
  if (tid >= K * N) return;
  int nn = tid / K, k = tid - nn * K;
  out[tid] = ld_any(in, k * N + nn, sbf);
}
__global__ void cvt_b(const void* __restrict__ in, u16* __restrict__ out,
                      int n) {
  __shared__ int sbf;
  if (threadIdx.x == 0) sbf = sniff_bf16(in, n);
  __syncthreads();
  int tid = blockIdx.x * 256 + threadIdx.x;
  if (tid < n) out[tid] = f2b(ld_any(in, tid, sbf));
}
__global__ void cvt_b_t(const void* __restrict__ in, u16* __restrict__ out,
                        int K, int N) {
  __shared__ int sbf;
  if (threadIdx.x == 0) sbf = sniff_bf16(in, K * N);
  __syncthreads();
  int tid = blockIdx.x * 256 + threadIdx.x;
  if (tid >= K * N) return;
  int nn = tid / K, k = tid - nn * K;
  out[tid] = f2b(ld_any(in, k * N + nn, sbf));
}

// ---------------------------------------------------------------------------
// f32 VALU GEMM (front end): C[M,N] = A[M,K] @ B[K,N] + bias. BT is N x ldb.
// ---------------------------------------------------------------------------
__global__ __launch_bounds__(256) void vgemm_f(
    const float* __restrict__ A, const float* __restrict__ BT,
    const float* __restrict__ bias, float* __restrict__ C, int M, int N, int K,
    int lda, int ldb, int ldc) {
  __shared__ float As[16 * 66];
  __shared__ float Bs[64 * 66];
  const int t = threadIdx.x;
  const int m0 = blockIdx.y * 16, n0 = blockIdx.x * 64;
  const int tx = t & 63, ty = t >> 6;
  float acc[4] = {0.f, 0.f, 0.f, 0.f};
  for (int k0 = 0; k0 < K; k0 += 64) {
    for (int idx = t; idx < 16 * 64; idx += 256) {
      int r = idx >> 6, k = idx & 63;
      int m = m0 + r, kk = k0 + k;
      As[r * 66 + k] = (m < M && kk < K) ? A[(size_t)m * lda + kk] : 0.f;
    }
    for (int idx = t; idx < 64 * 64; idx += 256) {
      int nr = idx >> 6, k = idx & 63;
      int nn = n0 + nr, kk = k0 + k;
      Bs[nr * 66 + k] = (nn < N && kk < K) ? BT[(size_t)nn * ldb + kk] : 0.f;
    }
    __syncthreads();
#pragma unroll 8
    for (int k = 0; k < 64; k++) {
      float b = Bs[tx * 66 + k];
#pragma unroll
      for (int q = 0; q < 4; q++) acc[q] += As[(ty * 4 + q) * 66 + k] * b;
    }
    __syncthreads();
  }
  int col = n0 + tx;
  if (col >= N) return;
  float bv = (bias != nullptr) ? bias[col] : 0.f;
#pragma unroll
  for (int q = 0; q < 4; q++) {
    int row = m0 + ty * 4 + q;
    if (row < M) C[(size_t)row * ldc + col] = acc[q] + bv;
  }
}

// ---------------------------------------------------------------------------
// bf16 VALU GEMM (MLP): optional pair-gather A, lrelu, bf16 out.
// ---------------------------------------------------------------------------
template <int GATHER>
__global__ __launch_bounds__(256) void vgemm_h(
    const u16* __restrict__ A, const u16* __restrict__ BT,
    const u16* __restrict__ bias, u16* __restrict__ C, int M, int N, int K,
    int lda, int ldb, int ldc, float slope, const u16* __restrict__ emb,
    const int* __restrict__ posp, const int* __restrict__ negp, int npos,
    int mbase) {
  __shared__ float As[16 * 66];
  __shared__ float Bs[64 * 66];
  const int t = threadIdx.x;
  const int m0 = blockIdx.y * 16, n0 = blockIdx.x * 64;
  const int tx = t & 63, ty = t >> 6;
  float acc[4] = {0.f, 0.f, 0.f, 0.f};
  for (int k0 = 0; k0 < K; k0 += 64) {
    for (int idx = t; idx < 16 * 64; idx += 256) {
      int r = idx >> 6, k = idx & 63;
      int m = m0 + r, kk = k0 + k;
      float v = 0.f;
      if (m < M && kk < K) {
        if (GATHER) {
          int g = mbase + m;
          const int* pp = (g < npos) ? (posp + 2 * g) : (negp + 2 * (g - npos));
          v = b2f(emb[(size_t)pp[0] * lda + kk]) *
              b2f(emb[(size_t)(1500 + pp[1]) * lda + kk]);
        } else {
          v = b2f(A[(size_t)m * lda + kk]);
        }
      }
      As[r * 66 + k] = v;
    }
    for (int idx = t; idx < 64 * 64; idx += 256) {
      int nr = idx >> 6, k = idx & 63;
      int nn = n0 + nr, kk = k0 + k;
      Bs[nr * 66 + k] = (nn < N && kk < K) ? b2f(BT[(size_t)nn * ldb + kk]) : 0.f;
    }
    __syncthreads();
#pragma unroll 8
    for (int k = 0; k < 64; k++) {
      float b = Bs[tx * 66 + k];
#pragma unroll
      for (int q = 0; q < 4; q++) acc[q] += As[(ty * 4 + q) * 66 + k] * b;
    }
    __syncthreads();
  }
  int col = n0 + tx;
  if (col >= N) return;
  float bv = (bias != nullptr) ? b2f(bias[col]) : 0.f;
#pragma unroll
  for (int q = 0; q < 4; q++) {
    int row = m0 + ty * 4 + q;
    if (row < M) {
      float v = acc[q] + bv;
      v = (v > 0.f) ? v : v * slope;
      C[(size_t)row * ldc + col] = f2b(v);
    }
  }
}

__global__ void k_zero2(int* __restrict__ a, int* __restrict__ b, int n) {
  int tid = blockIdx.x * 256 + threadIdx.x;
  if (tid < n) { a[tid] = 0; b[tid] = 0; }
}

// ---------------------------------------------------------------------------
// GAT
// ---------------------------------------------------------------------------
__global__ void k_edge_e(const float* __restrict__ xl,
                         const float* __restrict__ xr,
                         const int* __restrict__ ei,
                         const float* __restrict__ att, float* __restrict__ e,
                         int E, int Etot) {
  __shared__ float attf[1024];
  int t = threadIdx.x;
  for (int i = t; i < 1024; i += 256) attf[i] = att[i];
  __syncthreads();
  int lane = t & 63;
  int eid = blockIdx.x * 4 + (t >> 6);
  if (eid >= Etot) return;
  int src = (eid < E) ? ei[eid] : (eid - E);
  int dst = (eid < E) ? ei[E + eid] : (eid - E);
  const float* pl = xl + (size_t)src * 1024;
  const float* pr = xr + (size_t)dst * 1024;
#pragma unroll
  for (int h = 0; h < 8; h++) {
    float a0 = pl[h * 128 + lane] + pr[h * 128 + lane];
    float a1 = pl[h * 128 + 64 + lane] + pr[h * 128 + 64 + lane];
    a0 = (a0 > 0.f) ? a0 : 0.2f * a0;
    a1 = (a1 > 0.f) ? a1 : 0.2f * a1;
    float p = a0 * attf[h * 128 + lane] + a1 * attf[h * 128 + 64 + lane];
#pragma unroll
    for (int off = 32; off; off >>= 1) p += __shfl_xor(p, off);
    if (lane == 0) e[(size_t)eid * 8 + h] = p;
  }
}

__global__ void k_count(const int* __restrict__ ei, int* __restrict__ cnt,
                        int E, int Etot) {
  int tid = blockIdx.x * 256 + threadIdx.x;
  if (tid >= Etot) return;
  int dst = (tid < E) ? ei[E + tid] : (tid - E);
  atomicAdd(&cnt[dst], 1);
}

__global__ void k_scan(const int* __restrict__ cnt, int* __restrict__ rowstart,
                       int Nn) {
  __shared__ int part[257];
  int t = threadIdx.x;
  int chunk = (Nn + 255) / 256;
  int b = t * chunk;
  int en = b + chunk; if (en > Nn) en = Nn;
  int s = 0;
  for (int i = b; i < en; i++) s += cnt[i];
  part[t] = s;
  __syncthreads();
  if (t == 0) {
    int acc = 0;
    for (int i = 0; i < 256; i++) { int v = part[i]; part[i] = acc; acc += v; }
    part[256] = acc;
  }
  __syncthreads();
  int run = part[t];
  for (int i = b; i < en; i++) { rowstart[i] = run; run += cnt[i]; }
  if (t == 0) rowstart[Nn] = part[256];
}

__global__ void k_scatter(const int* __restrict__ ei,
                          const int* __restrict__ rowstart,
                          int* __restrict__ cur, int* __restrict__ csr, int E,
                          int Etot) {
  int tid = blockIdx.x * 256 + threadIdx.x;
  if (tid >= Etot) return;
  int dst = (tid < E) ? ei[E + tid] : (tid - E);
  int p = atomicAdd(&cur[dst], 1);
  unsigned idx = (unsigned)(rowstart[dst] + p);
  if (idx < (unsigned)Etot) csr[idx] = tid;
}

__global__ void k_softmax(const float* __restrict__ e,
                          const int* __restrict__ csr,
                          const int* __restrict__ rowstart,
                          float* __restrict__ wgt, int Nn, int Etot) {
  int t = threadIdx.x;
  int lane = t & 63;
  int d = blockIdx.x * 4 + (t >> 6);
  if (d >= Nn) return;
  int rs = rowstart[d], re = rowstart[d + 1];
  for (int h = 0; h < 8; h++) {
    float mx = -3.0e38f;
    for (int i = rs + lane; i < re; i += 64) {
      unsigned eid = (unsigned)csr[i];
      if (eid < (unsigned)Etot) mx = fmaxf(mx, e[(size_t)eid * 8 + h]);
    }
#pragma unroll
    for (int off = 32; off; off >>= 1) mx = fmaxf(mx, __shfl_xor(mx, off));
    if (mx < -1.0e37f) mx = 0.f;
    float s = 0.f;
    for (int i = rs + lane; i < re; i += 64) {
      unsigned eid = (unsigned)csr[i];
      if (eid < (unsigned)Etot) s += expf(e[(size_t)eid * 8 + h] - mx);
    }
#pragma unroll
    for (int off = 32; off; off >>= 1) s += __shfl_xor(s, off);
    float inv = (s > 0.f) ? 1.f / s : 0.f;
    for (int i = rs + lane; i < re; i += 64) {
      unsigned eid = (unsigned)csr[i];
      if (eid < (unsigned)Etot)
        wgt[(size_t)eid * 8 + h] = expf(e[(size_t)eid * 8 + h] - mx) * inv;
    }
  }
}

__global__ void k_aggregate(const float* __restrict__ wgt,
                            const float* __restrict__ xl,
                            const int* __restrict__ ei,
                            const int* __restrict__ csr,
                            const int* __restrict__ rowstart,
                            const float* __restrict__ gbias,
                            float* __restrict__ res, int E, int Etot) {
  int d = blockIdx.x;
  int t = threadIdx.x;
  int c = t & 127, hb = t >> 7;
  int rs = rowstart[d], re = rowstart[d + 1];
  float acc[4] = {0.f, 0.f, 0.f, 0.f};
  for (int i = rs; i < re; i++) {
    unsigned eid = (unsigned)csr[i];
    if (eid >= (unsigned)Etot) continue;
    int src = (eid < (unsigned)E) ? ei[eid] : (int)(eid - E);
    const float* px = xl + (size_t)src * 1024 + hb * 512 + c;
    const float* pw = wgt + (size_t)eid * 8 + hb * 4;
#pragma unroll
    for (int q = 0; q < 4; q++) acc[q] += pw[q] * px[q * 128];
  }
#pragma unroll
  for (int q = 0; q < 4; q++) {
    int idx = (hb * 4 + q) * 128 + c;
    res[(size_t)d * 1024 + idx] = acc[q] + gbias[idx];
  }
}

// ---------------------------------------------------------------------------
// CNN: f32 in, f32 out to d_out, bf16 emb copy for MLP.
// ---------------------------------------------------------------------------
__global__ void k_cnn(const float* __restrict__ res,
                      const float* __restrict__ cw1, const float* __restrict__ cb1,
                      const float* __restrict__ cw4, const float* __restrict__ cb4,
                      const float* __restrict__ cw16, const float* __restrict__ cb16,
                      const float* __restrict__ cw32, const float* __restrict__ cb32,
                      float* __restrict__ outc, u16* __restrict__ emb) {
  __shared__ float xs[1024];
  __shared__ float wc[2544];
  __shared__ float cb[24];
  int t = threadIdx.x, node = blockIdx.x;
  for (int i = t; i < 1024; i += 256) xs[i] = res[(size_t)node * 1024 + i];
  for (int i = t; i < 48; i += 256) wc[i] = cw1[i];
  for (int i = t; i < 192; i += 256) wc[48 + i] = cw4[i];
  for (int i = t; i < 768; i += 256) wc[240 + i] = cw16[i];
  for (int i = t; i < 1536; i += 256) wc[1008 + i] = cw32[i];
  if (t < 6) {
    cb[t] = cb1[t];
    cb[6 + t] = cb4[t];
    cb[12 + t] = cb16[t];
    cb[18 + t] = cb32[t];
  }
  __syncthreads();
  for (int o = t; o < 2778; o += 256) {
    int k, W, base, boff, rr;
    if (o < 768)       { k = 1;  W = 128; base = 0;    boff = 0;  rr = o; }
    else if (o < 1518) { k = 4;  W = 125; base = 48;   boff = 6;  rr = o - 768; }
    else if (o < 2196) { k = 16; W = 113; base = 240;  boff = 12; rr = o - 1518; }
    else               { k = 32; W = 97;  base = 1008; boff = 18; rr = o - 2196; }
    int oc = rr / W, wp = rr - oc * W;
    const float* wgt = &wc[base + oc * 8 * k];
    float v = cb[boff + oc];
    for (int h = 0; h < 8; h++)
      for (int j = 0; j < k; j++) v += xs[h * 128 + wp + j] * wgt[h * k + j];
    v = fmaxf(v, 0.f);
    outc[(size_t)node * 2778 + o] = v;
    emb[(size_t)node * 2778 + o] = f2b(v);
  }
}

// ---------------------------------------------------------------------------
__global__ void k_gemv_sig(const u16* __restrict__ hh3,
                           const u16* __restrict__ w4, float* __restrict__ pred,
                           int M, int K, int ldk) {
  __shared__ float ws[464];
  int t = threadIdx.x;
  for (int i = t; i < K; i += 256) ws[i] = b2f(w4[i]);
  __syncthreads();
  int lane = t & 63;
  int m = blockIdx.x * 4 + (t >> 6);
  if (m >= M) return;
  const u16* p = hh3 + (size_t)m * ldk;
  float s = 0.f;
  for (int i = lane; i < K; i += 64) s += b2f(p[i]) * ws[i];
#pragma unroll
  for (int off = 32; off; off >>= 1) s += __shfl_xor(s, off);
  if (!(s == s)) s = 0.f;  // NaN guard
  s = fminf(fmaxf(s, -30.f), 30.f);
  if (lane == 0) pred[m] = 1.f / (1.f + expf(-s));
}

__global__ void k_labels(float* __restrict__ lab, int P) {
  int tid = blockIdx.x * 256 + threadIdx.x;
  if (tid < 2 * P) lab[tid] = (tid < P) ? 1.f : 0.f;
}

__global__ void k_sentinel(float* __restrict__ pred, int M, float val) {
  int tid = blockIdx.x * 256 + threadIdx.x;
  if (tid < M) pred[tid] = val;
}

// ---------------------------------------------------------------------------
extern "C" void kernel_launch(void* const* d_in, const int* in_sizes, int n_in,
                              void* d_out, int out_size, void* d_ws,
                              size_t ws_size, hipStream_t stream) {
  (void)in_sizes; (void)n_in; (void)out_size;
  const int* ei = (const int*)d_in[2];
  const int* posp = (const int*)d_in[3];
  const int* negp = (const int*)d_in[4];

  const int E = 80000, ET = 82300, P = 40000, M = 80000;

  float* outp = (float*)d_out;       // pred   [80000] f32
  float* outl = outp + 80000;        // labels [80000] f32
  float* outc = outp + 160000;       // cnn    [2300*2778] f32

  k_labels<<<(2 * P + 255) / 256, 256, 0, stream>>>(outl, P);

  char* base = (char*)d_ws;
  size_t off = 0;
  auto alloc = [&](size_t bytes) -> void* {
    void* p = base + off;
    off = (off + bytes + 255) & ~(size_t)255;
    return p;
  };
  // front-end f32 canonical copies
  float* mic_f = (float*)alloc((size_t)1500 * 1500 * 4);
  float* dis_f = (float*)alloc((size_t)800 * 800 * 4);
  float* WmT_f = (float*)alloc((size_t)128 * 1500 * 4);
  float* WdT_f = (float*)alloc((size_t)128 * 800 * 4);
  float* WlT_f = (float*)alloc((size_t)1024 * 128 * 4);
  float* WrT_f = (float*)alloc((size_t)1024 * 128 * 4);
  float* bl_f = (float*)alloc(1024 * 4);
  float* br_f = (float*)alloc(1024 * 4);
  float* att_f = (float*)alloc(1024 * 4);
  float* gbias_f = (float*)alloc(1024 * 4);
  float* cw1_f = (float*)alloc(48 * 4);
  float* cb1_f = (float*)alloc(6 * 4);
  float* cw4_f = (float*)alloc(192 * 4);
  float* cb4_f = (float*)alloc(6 * 4);
  float* cw16_f = (float*)alloc(768 * 4);
  float* cb16_f = (float*)alloc(6 * 4);
  float* cw32_f = (float*)alloc(1536 * 4);
  float* cb32_f = (float*)alloc(6 * 4);
  // MLP bf16 canonical copies (transposed weights)
  u16* m1T = (u16*)alloc((size_t)1389 * 2778 * 2);
  u16* m2T = (u16*)alloc((size_t)694 * 1389 * 2);
  u16* m3T = (u16*)alloc((size_t)463 * 694 * 2);
  u16* mb1_b = (u16*)alloc(1389 * 2);
  u16* mb2_b = (u16*)alloc(694 * 2);
  u16* mb3_b = (u16*)alloc(463 * 2);
  u16* mw4_b = (u16*)alloc(463 * 2);
  // intermediates
  float* hbuf = (float*)alloc((size_t)2300 * 128 * 4);
  float* xlf = (float*)alloc((size_t)2300 * 1024 * 4);
  float* xrf = (float*)alloc((size_t)2300 * 1024 * 4);
  float* resf = xrf;  // xr dead after k_edge_e
  float* ebuf = (float*)alloc((size_t)ET * 8 * 4);
  float* wbuf = (float*)alloc((size_t)ET * 8 * 4);
  u16* emb = (u16*)alloc((size_t)2300 * 2778 * 2);
  int* cnt = (int*)alloc(2300 * 4);
  int* rowst = (int*)alloc(2304 * 4);
  int* cur = (int*)alloc(2300 * 4);
  int* csr = (int*)alloc((size_t)ET * 4);
  size_t fixed_end = off;

  const size_t per_row = (size_t)(1389 + 694) * 2;
  size_t avail = (ws_size > fixed_end) ? (ws_size - fixed_end) : 0;
  long long Rll = (long long)(avail / per_row);
  int R = (Rll > M) ? M : (int)Rll;
  R &= ~127;
  if (fixed_end > ws_size || R < 128) {
    k_sentinel<<<(M + 255) / 256, 256, 0, stream>>>(outp, M, 0.25f);
    return;
  }
  u16* hh1 = (u16*)(base + fixed_end);
  u16* hh2 = hh1 + (size_t)R * 1389;

  k_zero2<<<(2300 + 255) / 256, 256, 0, stream>>>(cnt, cur, 2300);

  // ---- canonicalize inputs ----
  cvt_f<<<(2250000 + 255) / 256, 256, 0, stream>>>(d_in[0], mic_f, 2250000);
  cvt_f<<<(640000 + 255) / 256, 256, 0, stream>>>(d_in[1], dis_f, 640000);
  cvt_f_t<<<(192000 + 255) / 256, 256, 0, stream>>>(d_in[6], WmT_f, 1500, 128);
  cvt_f_t<<<(102400 + 255) / 256, 256, 0, stream>>>(d_in[7], WdT_f, 800, 128);
  cvt_f_t<<<(131072 + 255) / 256, 256, 0, stream>>>(d_in[8], WlT_f, 128, 1024);
  cvt_f<<<4, 256, 0, stream>>>(d_in[9], bl_f, 1024);
  cvt_f_t<<<(131072 + 255) / 256, 256, 0, stream>>>(d_in[10], WrT_f, 128, 1024);
  cvt_f<<<4, 256, 0, stream>>>(d_in[11], br_f, 1024);
  cvt_f<<<4, 256, 0, stream>>>(d_in[12], att_f, 1024);
  cvt_f<<<4, 256, 0, stream>>>(d_in[13], gbias_f, 1024);
  cvt_f<<<1, 256, 0, stream>>>(d_in[14], cw1_f, 48);
  cvt_f<<<1, 256, 0, stream>>>(d_in[15], cb1_f, 6);
  cvt_f<<<1, 256, 0, stream>>>(d_in[16], cw4_f, 192);
  cvt_f<<<1, 256, 0, stream>>>(d_in[17], cb4_f, 6);
  cvt_f<<<3, 256, 0, stream>>>(d_in[18], cw16_f, 768);
  cvt_f<<<1, 256, 0, stream>>>(d_in[19], cb16_f, 6);
  cvt_f<<<6, 256, 0, stream>>>(d_in[20], cw32_f, 1536);
  cvt_f<<<1, 256, 0, stream>>>(d_in[21], cb32_f, 6);
  cvt_b_t<<<(3858642 + 255) / 256, 256, 0, stream>>>(d_in[22], m1T, 2778, 1389);
  cvt_b<<<(1389 + 255) / 256, 256, 0, stream>>>(d_in[23], mb1_b, 1389);
  cvt_b_t<<<(963966 + 255) / 256, 256, 0, stream>>>(d_in[24], m2T, 1389, 694);
  cvt_b<<<(694 + 255) / 256, 256, 0, stream>>>(d_in[25], mb2_b, 694);
  cvt_b_t<<<(321322 + 255) / 256, 256, 0, stream>>>(d_in[26], m3T, 694, 463);
  cvt_b<<<(463 + 255) / 256, 256, 0, stream>>>(d_in[27], mb3_b, 463);
  cvt_b<<<(463 + 255) / 256, 256, 0, stream>>>(d_in[28], mw4_b, 463);

  // ---- h = [mic@Wm ; dis@Wd] (f32) ----
  vgemm_f<<<dim3(2, 94), 256, 0, stream>>>(mic_f, WmT_f, nullptr, hbuf, 1500,
                                           128, 1500, 1500, 1500, 128);
  vgemm_f<<<dim3(2, 50), 256, 0, stream>>>(dis_f, WdT_f, nullptr,
                                           hbuf + (size_t)1500 * 128, 800, 128,
                                           800, 800, 800, 128);
  // ---- xl, xr (f32) ----
  vgemm_f<<<dim3(16, 144), 256, 0, stream>>>(hbuf, WlT_f, bl_f, xlf, 2300,
                                             1024, 128, 128, 128, 1024);
  vgemm_f<<<dim3(16, 144), 256, 0, stream>>>(hbuf, WrT_f, br_f, xrf, 2300,
                                             1024, 128, 128, 128, 1024);

  // ---- GAT ----
  k_edge_e<<<(ET + 3) / 4, 256, 0, stream>>>(xlf, xrf, ei, att_f, ebuf, E, ET);
  k_count<<<(ET + 255) / 256, 256, 0, stream>>>(ei, cnt, E, ET);
  k_scan<<<1, 256, 0, stream>>>(cnt, rowst, 2300);
  k_scatter<<<(ET + 255) / 256, 256, 0, stream>>>(ei, rowst, cur, csr, E, ET);
  k_softmax<<<(2300 + 3) / 4, 256, 0, stream>>>(ebuf, csr, rowst, wbuf, 2300, ET);
  k_aggregate<<<2300, 256, 0, stream>>>(wbuf, xlf, ei, csr, rowst, gbias_f,
                                        resf, E, ET);

  // ---- CNN (f32 out + bf16 emb) ----
  k_cnn<<<2300, 256, 0, stream>>>(resf, cw1_f, cb1_f, cw4_f, cb4_f, cw16_f,
                                  cb16_f, cw32_f, cb32_f, outc, emb);

  // ---- MLP (chunked, bf16; gather fused into L1 staging) ----
  for (int c0 = 0; c0 < M; c0 += R) {
    int rows = (M - c0 < R) ? (M - c0) : R;
    int gby = (rows + 15) / 16;
    vgemm_h<1><<<dim3(22, gby), 256, 0, stream>>>(
        nullptr, m1T, mb1_b, hh1, rows, 1389, 2778, 2778, 2778, 1389, 0.01f,
        emb, posp, negp, P, c0);
    vgemm_h<0><<<dim3(11, gby), 256, 0, stream>>>(
        hh1, m2T, mb2_b, hh2, rows, 694, 1389, 1389, 1389, 694, 0.01f, nullptr,
        nullptr, nullptr, 0, 0);
    vgemm_h<0><<<dim3(8, gby), 256, 0, stream>>>(
        hh2, m3T, mb3_b, hh1, rows, 463, 694, 694, 694, 463, 0.01f, nullptr,
        nullptr, nullptr, 0, 0);
    k_gemv_sig<<<(rows + 3) / 4, 256, 0, stream>>>(hh1, mw4_b, outp + c0, rows,
                                                   463, 463);
  }
}

// Round 10
// 3191.220 us; speedup vs baseline: 11.2475x; 11.2475x over previous
//
#include <hip/hip_runtime.h>

// ===========================================================================
// GAT_CNN_DASE :: gfx950 :: R10.
// R9 passed (35.9 ms) — MLP-L1 VALU GEMM = ~35 ms (VALUBusy 70%, MfmaUtil 0).
// R10: MLP L1/L2/L3 -> 128x128-tile MFMA bf16 GEMM (16x16x32), K-padded
// strides (2784/1408/704/480), pair-gather fused into A-staging.
// Front end (f32 VALU GEMMs + GAT + CNN) unchanged from R9.
// ===========================================================================

typedef unsigned short u16;
typedef __attribute__((ext_vector_type(8))) short bf16x8;
typedef __attribute__((ext_vector_type(4))) float f32x4;

__device__ __forceinline__ float b2f(u16 u) {
  unsigned v = ((unsigned)u) << 16;
  return __builtin_bit_cast(float, v);
}
__device__ __forceinline__ u16 f2b(float f) {
  unsigned x = __builtin_bit_cast(unsigned, f);
  x += 0x7fffu + ((x >> 16) & 1u);
  return (u16)(x >> 16);
}

// bf16 data: ~100% of u16s have exponent in [100,140]; f32-as-u16: ~58%.
__device__ __forceinline__ int sniff_bf16(const void* p, int n) {
  const u16* pu = (const u16*)p;
  int ns = n < 128 ? n : 128;
  int sane = 0, nz = 0;
  for (int i = 0; i < ns; i++) {
    u16 v = pu[i];
    if (v) nz++;
    int e = (v >> 7) & 0xFF;
    if (e >= 100 && e <= 140) sane++;
  }
  return (nz == 0) || (sane * 8 >= ns * 7);
}
__device__ __forceinline__ float ld_any(const void* p, int i, int isbf) {
  return isbf ? b2f(((const u16*)p)[i]) : ((const float*)p)[i];
}

__global__ void cvt_f(const void* __restrict__ in, float* __restrict__ out,
                      int n) {
  __shared__ int sbf;
  if (threadIdx.x == 0) sbf = sniff_bf16(in, n);
  __syncthreads();
  int tid = blockIdx.x * 256 + threadIdx.x;
  if (tid < n) out[tid] = ld_any(in, tid, sbf);
}
// in[k*N+n] -> out[n*K+k]
__global__ void cvt_f_t(const void* __restrict__ in, float* __restrict__ out,
                        int K, int N) {
  __shared__ int sbf;
  if (threadIdx.x == 0) sbf = sniff_bf16(in, K * N);
  __syncthreads();
  int tid = blockIdx.x * 256 + threadIdx.x;
  if (tid >= K * N) return;
  int nn = tid / K, k = tid - nn * K;
  out[tid] = ld_any(in, k * N + nn, sbf);
}
__global__ void cvt_b(const void* __restrict__ in, u16* __restrict__ out,
                      int n) {
  __shared__ int sbf;
  if (threadIdx.x == 0) sbf = sniff_bf16(in, n);
  __syncthreads();
  int tid = blockIdx.x * 256 + threadIdx.x;
  if (tid < n) out[tid] = f2b(ld_any(in, tid, sbf));
}
// in[k*N+n] -> out[n*Kpad+k], zero pad k in [K,Kpad)
__global__ void cvt_b_tp(const void* __restrict__ in, u16* __restrict__ out,
                         int K, int N, int Kpad) {
  __shared__ int sbf;
  if (threadIdx.x == 0) sbf = sniff_bf16(in, K * N);
  __syncthreads();
  int tid = blockIdx.x * 256 + threadIdx.x;
  if (tid >= N * Kpad) return;
  int nn = tid / Kpad, k = tid - nn * Kpad;
  out[tid] = (k < K) ? f2b(ld_any(in, (size_t)k * N + nn, sbf)) : (u16)0;
}

// ---------------------------------------------------------------------------
// MFMA bf16 GEMM: C[M,N] = lrelu(A[M,Kpad] @ B + bias). BT is N x ldb
// (K-contiguous). GATHER=1: A[m][k] = emb[p0[mbase+m]][k]*emb[1500+p1..][k].
// 128x128 tile, BK=32, 4 waves of 64x64, 16x16x32 MFMA. Epilogue zero-fills
// cols [N, ldc) so output is a valid K-padded A for the next GEMM.
// C/D layout (m89-verified): col = lane&15, row = (lane>>4)*4 + reg.
// ---------------------------------------------------------------------------
template <int GATHER>
__global__ __launch_bounds__(256, 2) void mgemm(
    const u16* __restrict__ A, const u16* __restrict__ BT,
    const u16* __restrict__ bias, u16* __restrict__ C, int M, int N, int Kpad,
    int lda, int ldb, int ldc, float slope, const u16* __restrict__ emb,
    const int* __restrict__ posp, const int* __restrict__ negp, int npos,
    int mbase) {
  __shared__ u16 As[128 * 32];
  __shared__ u16 Bs[128 * 32];
  const int t = threadIdx.x;
  const int lane = t & 63, wave = t >> 6;
  const int quad = lane >> 4, l16 = lane & 15;
  const int wm = wave >> 1, wn = wave & 1;
  const int m0 = blockIdx.y * 128, n0 = blockIdx.x * 128;

  const int r0 = t >> 2;       // staging row 0..63 (+64 second half)
  const int kc = (t & 3) * 8;  // k-chunk 0/8/16/24

  f32x4 zero4 = {0.f, 0.f, 0.f, 0.f};
  f32x4 acc[4][4];
#pragma unroll
  for (int i = 0; i < 4; i++)
#pragma unroll
    for (int j = 0; j < 4; j++) acc[i][j] = zero4;

  int ga0 = 0, ga1 = 0, gb0 = 0, gb1 = 0;
  if (GATHER) {
    int m = m0 + r0;
    if (m < M) {
      int g = mbase + m;
      const int* pp = (g < npos) ? (posp + 2 * g) : (negp + 2 * (g - npos));
      ga0 = pp[0]; ga1 = pp[1];
    }
    int m2 = m0 + r0 + 64;
    if (m2 < M) {
      int g = mbase + m2;
      const int* pp = (g < npos) ? (posp + 2 * g) : (negp + 2 * (g - npos));
      gb0 = pp[0]; gb1 = pp[1];
    }
  }

  for (int k0 = 0; k0 < Kpad; k0 += 32) {
#pragma unroll
    for (int half = 0; half < 2; half++) {
      int r = r0 + half * 64;
      int m = m0 + r;
      bf16x8 v = {0, 0, 0, 0, 0, 0, 0, 0};
      if (m < M) {
        if (GATHER) {
          int i0 = half ? gb0 : ga0, i1 = half ? gb1 : ga1;
          bf16x8 x = *(const bf16x8*)(emb + (size_t)i0 * lda + k0 + kc);
          bf16x8 y = *(const bf16x8*)(emb + (size_t)(1500 + i1) * lda + k0 + kc);
#pragma unroll
          for (int j = 0; j < 8; j++) {
            float p = b2f((u16)x[j]) * b2f((u16)y[j]);
            ((u16*)&v)[j] = f2b(p);
          }
        } else {
          v = *(const bf16x8*)(A + (size_t)m * lda + k0 + kc);
        }
      }
      *(bf16x8*)(&As[r * 32 + kc]) = v;
      int n = n0 + r;
      bf16x8 bv = {0, 0, 0, 0, 0, 0, 0, 0};
      if (n < N) bv = *(const bf16x8*)(BT + (size_t)n * ldb + k0 + kc);
      *(bf16x8*)(&Bs[r * 32 + kc]) = bv;
    }
    __syncthreads();
    bf16x8 af[4], bfr[4];
#pragma unroll
    for (int i = 0; i < 4; i++)
      af[i] = *(const bf16x8*)(&As[(wm * 64 + i * 16 + l16) * 32 + quad * 8]);
#pragma unroll
    for (int j = 0; j < 4; j++)
      bfr[j] = *(const bf16x8*)(&Bs[(wn * 64 + j * 16 + l16) * 32 + quad * 8]);
#pragma unroll
    for (int i = 0; i < 4; i++)
#pragma unroll
      for (int j = 0; j < 4; j++)
        acc[i][j] = __builtin_amdgcn_mfma_f32_16x16x32_bf16(af[i], bfr[j],
                                                            acc[i][j], 0, 0, 0);
    __syncthreads();
  }

#pragma unroll
  for (int j = 0; j < 4; j++) {
    int col = n0 + wn * 64 + j * 16 + l16;
    if (col >= ldc) continue;
    float bv = 0.f;
    if (bias != nullptr && col < N) bv = b2f(bias[col]);
#pragma unroll
    for (int i = 0; i < 4; i++) {
#pragma unroll
      for (int r = 0; r < 4; r++) {
        int row = m0 + wm * 64 + i * 16 + quad * 4 + r;
        if (row >= M) continue;
        float v;
        if (col < N) {
          v = acc[i][j][r] + bv;
          v = (v > 0.f) ? v : v * slope;
        } else {
          v = 0.f;  // zero-fill pad cols for next GEMM's K-pad
        }
        C[(size_t)row * ldc + col] = f2b(v);
      }
    }
  }
}

// ---------------------------------------------------------------------------
// f32 VALU GEMM (front end)
// ---------------------------------------------------------------------------
__global__ __launch_bounds__(256) void vgemm_f(
    const float* __restrict__ A, const float* __restrict__ BT,
    const float* __restrict__ bias, float* __restrict__ C, int M, int N, int K,
    int lda, int ldb, int ldc) {
  __shared__ float As[16 * 66];
  __shared__ float Bs[64 * 66];
  const int t = threadIdx.x;
  const int m0 = blockIdx.y * 16, n0 = blockIdx.x * 64;
  const int tx = t & 63, ty = t >> 6;
  float acc[4] = {0.f, 0.f, 0.f, 0.f};
  for (int k0 = 0; k0 < K; k0 += 64) {
    for (int idx = t; idx < 16 * 64; idx += 256) {
      int r = idx >> 6, k = idx & 63;
      int m = m0 + r, kk = k0 + k;
      As[r * 66 + k] = (m < M && kk < K) ? A[(size_t)m * lda + kk] : 0.f;
    }
    for (int idx = t; idx < 64 * 64; idx += 256) {
      int nr = idx >> 6, k = idx & 63;
      int nn = n0 + nr, kk = k0 + k;
      Bs[nr * 66 + k] = (nn < N && kk < K) ? BT[(size_t)nn * ldb + kk] : 0.f;
    }
    __syncthreads();
#pragma unroll 8
    for (int k = 0; k < 64; k++) {
      float b = Bs[tx * 66 + k];
#pragma unroll
      for (int q = 0; q < 4; q++) acc[q] += As[(ty * 4 + q) * 66 + k] * b;
    }
    __syncthreads();
  }
  int col = n0 + tx;
  if (col >= N) return;
  float bv = (bias != nullptr) ? bias[col] : 0.f;
#pragma unroll
  for (int q = 0; q < 4; q++) {
    int row = m0 + ty * 4 + q;
    if (row < M) C[(size_t)row * ldc + col] = acc[q] + bv;
  }
}

__global__ void k_zero2(int* __restrict__ a, int* __restrict__ b, int n) {
  int tid = blockIdx.x * 256 + threadIdx.x;
  if (tid < n) { a[tid] = 0; b[tid] = 0; }
}

// ---------------------------------------------------------------------------
// GAT
// ---------------------------------------------------------------------------
__global__ void k_edge_e(const float* __restrict__ xl,
                         const float* __restrict__ xr,
                         const int* __restrict__ ei,
                         const float* __restrict__ att, float* __restrict__ e,
                         int E, int Etot) {
  __shared__ float attf[1024];
  int t = threadIdx.x;
  for (int i = t; i < 1024; i += 256) attf[i] = att[i];
  __syncthreads();
  int lane = t & 63;
  int eid = blockIdx.x * 4 + (t >> 6);
  if (eid >= Etot) return;
  int src = (eid < E) ? ei[eid] : (eid - E);
  int dst = (eid < E) ? ei[E + eid] : (eid - E);
  const float* pl = xl + (size_t)src * 1024;
  const float* pr = xr + (size_t)dst * 1024;
#pragma unroll
  for (int h = 0; h < 8; h++) {
    float a0 = pl[h * 128 + lane] + pr[h * 128 + lane];
    float a1 = pl[h * 128 + 64 + lane] + pr[h * 128 + 64 + lane];
    a0 = (a0 > 0.f) ? a0 : 0.2f * a0;
    a1 = (a1 > 0.f) ? a1 : 0.2f * a1;
    float p = a0 * attf[h * 128 + lane] + a1 * attf[h * 128 + 64 + lane];
#pragma unroll
    for (int off = 32; off; off >>= 1) p += __shfl_xor(p, off);
    if (lane == 0) e[(size_t)eid * 8 + h] = p;
  }
}

__global__ void k_count(const int* __restrict__ ei, int* __restrict__ cnt,
                        int E, int Etot) {
  int tid = blockIdx.x * 256 + threadIdx.x;
  if (tid >= Etot) return;
  int dst = (tid < E) ? ei[E + tid] : (tid - E);
  atomicAdd(&cnt[dst], 1);
}

__global__ void k_scan(const int* __restrict__ cnt, int* __restrict__ rowstart,
                       int Nn) {
  __shared__ int part[257];
  int t = threadIdx.x;
  int chunk = (Nn + 255) / 256;
  int b = t * chunk;
  int en = b + chunk; if (en > Nn) en = Nn;
  int s = 0;
  for (int i = b; i < en; i++) s += cnt[i];
  part[t] = s;
  __syncthreads();
  if (t == 0) {
    int acc = 0;
    for (int i = 0; i < 256; i++) { int v = part[i]; part[i] = acc; acc += v; }
    part[256] = acc;
  }
  __syncthreads();
  int run = part[t];
  for (int i = b; i < en; i++) { rowstart[i] = run; run += cnt[i]; }
  if (t == 0) rowstart[Nn] = part[256];
}

__global__ void k_scatter(const int* __restrict__ ei,
                          const int* __restrict__ rowstart,
                          int* __restrict__ cur, int* __restrict__ csr, int E,
                          int Etot) {
  int tid = blockIdx.x * 256 + threadIdx.x;
  if (tid >= Etot) return;
  int dst = (tid < E) ? ei[E + tid] : (tid - E);
  int p = atomicAdd(&cur[dst], 1);
  unsigned idx = (unsigned)(rowstart[dst] + p);
  if (idx < (unsigned)Etot) csr[idx] = tid;
}

__global__ void k_softmax(const float* __restrict__ e,
                          const int* __restrict__ csr,
                          const int* __restrict__ rowstart,
                          float* __restrict__ wgt, int Nn, int Etot) {
  int t = threadIdx.x;
  int lane = t & 63;
  int d = blockIdx.x * 4 + (t >> 6);
  if (d >= Nn) return;
  int rs = rowstart[d], re = rowstart[d + 1];
  for (int h = 0; h < 8; h++) {
    float mx = -3.0e38f;
    for (int i = rs + lane; i < re; i += 64) {
      unsigned eid = (unsigned)csr[i];
      if (eid < (unsigned)Etot) mx = fmaxf(mx, e[(size_t)eid * 8 + h]);
    }
#pragma unroll
    for (int off = 32; off; off >>= 1) mx = fmaxf(mx, __shfl_xor(mx, off));
    if (mx < -1.0e37f) mx = 0.f;
    float s = 0.f;
    for (int i = rs + lane; i < re; i += 64) {
      unsigned eid = (unsigned)csr[i];
      if (eid < (unsigned)Etot) s += expf(e[(size_t)eid * 8 + h] - mx);
    }
#pragma unroll
    for (int off = 32; off; off >>= 1) s += __shfl_xor(s, off);
    float inv = (s > 0.f) ? 1.f / s : 0.f;
    for (int i = rs + lane; i < re; i += 64) {
      unsigned eid = (unsigned)csr[i];
      if (eid < (unsigned)Etot)
        wgt[(size_t)eid * 8 + h] = expf(e[(size_t)eid * 8 + h] - mx) * inv;
    }
  }
}

__global__ void k_aggregate(const float* __restrict__ wgt,
                            const float* __restrict__ xl,
                            const int* __restrict__ ei,
                            const int* __restrict__ csr,
                            const int* __restrict__ rowstart,
                            const float* __restrict__ gbias,
                            float* __restrict__ res, int E, int Etot) {
  int d = blockIdx.x;
  int t = threadIdx.x;
  int c = t & 127, hb = t >> 7;
  int rs = rowstart[d], re = rowstart[d + 1];
  float acc[4] = {0.f, 0.f, 0.f, 0.f};
  for (int i = rs; i < re; i++) {
    unsigned eid = (unsigned)csr[i];
    if (eid >= (unsigned)Etot) continue;
    int src = (eid < (unsigned)E) ? ei[eid] : (int)(eid - E);
    const float* px = xl + (size_t)src * 1024 + hb * 512 + c;
    const float* pw = wgt + (size_t)eid * 8 + hb * 4;
#pragma unroll
    for (int q = 0; q < 4; q++) acc[q] += pw[q] * px[q * 128];
  }
#pragma unroll
  for (int q = 0; q < 4; q++) {
    int idx = (hb * 4 + q) * 128 + c;
    res[(size_t)d * 1024 + idx] = acc[q] + gbias[idx];
  }
}

// ---------------------------------------------------------------------------
// CNN: f32 in, f32 out to d_out (stride 2778), bf16 emb (stride 2784, padded)
// ---------------------------------------------------------------------------
__global__ void k_cnn(const float* __restrict__ res,
                      const float* __restrict__ cw1, const float* __restrict__ cb1,
                      const float* __restrict__ cw4, const float* __restrict__ cb4,
                      const float* __restrict__ cw16, const float* __restrict__ cb16,
                      const float* __restrict__ cw32, const float* __restrict__ cb32,
                      float* __restrict__ outc, u16* __restrict__ emb) {
  __shared__ float xs[1024];
  __shared__ float wc[2544];
  __shared__ float cb[24];
  int t = threadIdx.x, node = blockIdx.x;
  for (int i = t; i < 1024; i += 256) xs[i] = res[(size_t)node * 1024 + i];
  for (int i = t; i < 48; i += 256) wc[i] = cw1[i];
  for (int i = t; i < 192; i += 256) wc[48 + i] = cw4[i];
  for (int i = t; i < 768; i += 256) wc[240 + i] = cw16[i];
  for (int i = t; i < 1536; i += 256) wc[1008 + i] = cw32[i];
  if (t < 6) {
    cb[t] = cb1[t];
    cb[6 + t] = cb4[t];
    cb[12 + t] = cb16[t];
    cb[18 + t] = cb32[t];
  }
  __syncthreads();
  for (int o = t; o < 2778; o += 256) {
    int k, W, base, boff, rr;
    if (o < 768)       { k = 1;  W = 128; base = 0;    boff = 0;  rr = o; }
    else if (o < 1518) { k = 4;  W = 125; base = 48;   boff = 6;  rr = o - 768; }
    else if (o < 2196) { k = 16; W = 113; base = 240;  boff = 12; rr = o - 1518; }
    else               { k = 32; W = 97;  base = 1008; boff = 18; rr = o - 2196; }
    int oc = rr / W, wp = rr - oc * W;
    const float* wgt = &wc[base + oc * 8 * k];
    float v = cb[boff + oc];
    for (int h = 0; h < 8; h++)
      for (int j = 0; j < k; j++) v += xs[h * 128 + wp + j] * wgt[h * k + j];
    v = fmaxf(v, 0.f);
    outc[(size_t)node * 2778 + o] = v;
    emb[(size_t)node * 2784 + o] = f2b(v);
  }
  if (t < 6) emb[(size_t)node * 2784 + 2778 + t] = 0;  // zero K-pad
}

// ---------------------------------------------------------------------------
__global__ void k_gemv_sig(const u16* __restrict__ hh3,
                           const u16* __restrict__ w4, float* __restrict__ pred,
                           int M, int K, int ldk) {
  __shared__ float ws[464];
  int t = threadIdx.x;
  for (int i = t; i < K; i += 256) ws[i] = b2f(w4[i]);
  __syncthreads();
  int lane = t & 63;
  int m = blockIdx.x * 4 + (t >> 6);
  if (m >= M) return;
  const u16* p = hh3 + (size_t)m * ldk;
  float s = 0.f;
  for (int i = lane; i < K; i += 64) s += b2f(p[i]) * ws[i];
#pragma unroll
  for (int off = 32; off; off >>= 1) s += __shfl_xor(s, off);
  if (!(s == s)) s = 0.f;
  s = fminf(fmaxf(s, -30.f), 30.f);
  if (lane == 0) pred[m] = 1.f / (1.f + expf(-s));
}

__global__ void k_labels(float* __restrict__ lab, int P) {
  int tid = blockIdx.x * 256 + threadIdx.x;
  if (tid < 2 * P) lab[tid] = (tid < P) ? 1.f : 0.f;
}

__global__ void k_sentinel(float* __restrict__ pred, int M, float val) {
  int tid = blockIdx.x * 256 + threadIdx.x;
  if (tid < M) pred[tid] = val;
}

// ---------------------------------------------------------------------------
extern "C" void kernel_launch(void* const* d_in, const int* in_sizes, int n_in,
                              void* d_out, int out_size, void* d_ws,
                              size_t ws_size, hipStream_t stream) {
  (void)in_sizes; (void)n_in; (void)out_size;
  const int* ei = (const int*)d_in[2];
  const int* posp = (const int*)d_in[3];
  const int* negp = (const int*)d_in[4];

  const int E = 80000, ET = 82300, P = 40000, M = 80000;

  float* outp = (float*)d_out;
  float* outl = outp + 80000;
  float* outc = outp + 160000;

  k_labels<<<(2 * P + 255) / 256, 256, 0, stream>>>(outl, P);

  char* base = (char*)d_ws;
  size_t off = 0;
  auto alloc = [&](size_t bytes) -> void* {
    void* p = base + off;
    off = (off + bytes + 255) & ~(size_t)255;
    return p;
  };
  // front-end f32 copies
  float* mic_f = (float*)alloc((size_t)1500 * 1500 * 4);
  float* dis_f = (float*)alloc((size_t)800 * 800 * 4);
  float* WmT_f = (float*)alloc((size_t)128 * 1500 * 4);
  float* WdT_f = (float*)alloc((size_t)128 * 800 * 4);
  float* WlT_f = (float*)alloc((size_t)1024 * 128 * 4);
  float* WrT_f = (float*)alloc((size_t)1024 * 128 * 4);
  float* bl_f = (float*)alloc(1024 * 4);
  float* br_f = (float*)alloc(1024 * 4);
  float* att_f = (float*)alloc(1024 * 4);
  float* gbias_f = (float*)alloc(1024 * 4);
  float* cw1_f = (float*)alloc(48 * 4);
  float* cb1_f = (float*)alloc(6 * 4);
  float* cw4_f = (float*)alloc(192 * 4);
  float* cb4_f = (float*)alloc(6 * 4);
  float* cw16_f = (float*)alloc(768 * 4);
  float* cb16_f = (float*)alloc(6 * 4);
  float* cw32_f = (float*)alloc(1536 * 4);
  float* cb32_f = (float*)alloc(6 * 4);
  // MLP bf16 copies, K-padded transposed weights
  u16* m1T = (u16*)alloc((size_t)1389 * 2784 * 2);   // K=2778 -> 2784
  u16* m2T = (u16*)alloc((size_t)694 * 1408 * 2);    // K=1389 -> 1408
  u16* m3T = (u16*)alloc((size_t)463 * 704 * 2);     // K=694  -> 704
  u16* mb1_b = (u16*)alloc(1389 * 2);
  u16* mb2_b = (u16*)alloc(694 * 2);
  u16* mb3_b = (u16*)alloc(463 * 2);
  u16* mw4_b = (u16*)alloc(463 * 2);
  // intermediates
  float* hbuf = (float*)alloc((size_t)2300 * 128 * 4);
  float* xlf = (float*)alloc((size_t)2300 * 1024 * 4);
  float* xrf = (float*)alloc((size_t)2300 * 1024 * 4);
  float* resf = xrf;  // xr dead after k_edge_e
  float* ebuf = (float*)alloc((size_t)ET * 8 * 4);
  float* wbuf = (float*)alloc((size_t)ET * 8 * 4);
  u16* emb = (u16*)alloc((size_t)2300 * 2784 * 2);   // K-padded
  int* cnt = (int*)alloc(2300 * 4);
  int* rowst = (int*)alloc(2304 * 4);
  int* cur = (int*)alloc(2300 * 4);
  int* csr = (int*)alloc((size_t)ET * 4);
  size_t fixed_end = off;

  const size_t per_row = (size_t)(1408 + 704) * 2;
  size_t avail = (ws_size > fixed_end) ? (ws_size - fixed_end) : 0;
  long long Rll = (long long)(avail / per_row);
  int R = (Rll > M) ? M : (int)Rll;
  R &= ~127;
  if (fixed_end > ws_size || R < 128) {
    k_sentinel<<<(M + 255) / 256, 256, 0, stream>>>(outp, M, 0.25f);
    return;
  }
  u16* hh1 = (u16*)(base + fixed_end);   // R x 1408 (ldc-padded)
  u16* hh2 = hh1 + (size_t)R * 1408;     // R x 704

  k_zero2<<<(2300 + 255) / 256, 256, 0, stream>>>(cnt, cur, 2300);

  // ---- canonicalize inputs ----
  cvt_f<<<(2250000 + 255) / 256, 256, 0, stream>>>(d_in[0], mic_f, 2250000);
  cvt_f<<<(640000 + 255) / 256, 256, 0, stream>>>(d_in[1], dis_f, 640000);
  cvt_f_t<<<(192000 + 255) / 256, 256, 0, stream>>>(d_in[6], WmT_f, 1500, 128);
  cvt_f_t<<<(102400 + 255) / 256, 256, 0, stream>>>(d_in[7], WdT_f, 800, 128);
  cvt_f_t<<<(131072 + 255) / 256, 256, 0, stream>>>(d_in[8], WlT_f, 128, 1024);
  cvt_f<<<4, 256, 0, stream>>>(d_in[9], bl_f, 1024);
  cvt_f_t<<<(131072 + 255) / 256, 256, 0, stream>>>(d_in[10], WrT_f, 128, 1024);
  cvt_f<<<4, 256, 0, stream>>>(d_in[11], br_f, 1024);
  cvt_f<<<4, 256, 0, stream>>>(d_in[12], att_f, 1024);
  cvt_f<<<4, 256, 0, stream>>>(d_in[13], gbias_f, 1024);
  cvt_f<<<1, 256, 0, stream>>>(d_in[14], cw1_f, 48);
  cvt_f<<<1, 256, 0, stream>>>(d_in[15], cb1_f, 6);
  cvt_f<<<1, 256, 0, stream>>>(d_in[16], cw4_f, 192);
  cvt_f<<<1, 256, 0, stream>>>(d_in[17], cb4_f, 6);
  cvt_f<<<3, 256, 0, stream>>>(d_in[18], cw16_f, 768);
  cvt_f<<<1, 256, 0, stream>>>(d_in[19], cb16_f, 6);
  cvt_f<<<6, 256, 0, stream>>>(d_in[20], cw32_f, 1536);
  cvt_f<<<1, 256, 0, stream>>>(d_in[21], cb32_f, 6);
  cvt_b_tp<<<((1389 * 2784) + 255) / 256, 256, 0, stream>>>(d_in[22], m1T, 2778, 1389, 2784);
  cvt_b<<<(1389 + 255) / 256, 256, 0, stream>>>(d_in[23], mb1_b, 1389);
  cvt_b_tp<<<((694 * 1408) + 255) / 256, 256, 0, stream>>>(d_in[24], m2T, 1389, 694, 1408);
  cvt_b<<<(694 + 255) / 256, 256, 0, stream>>>(d_in[25], mb2_b, 694);
  cvt_b_tp<<<((463 * 704) + 255) / 256, 256, 0, stream>>>(d_in[26], m3T, 694, 463, 704);
  cvt_b<<<(463 + 255) / 256, 256, 0, stream>>>(d_in[27], mb3_b, 463);
  cvt_b<<<(463 + 255) / 256, 256, 0, stream>>>(d_in[28], mw4_b, 463);

  // ---- front end (unchanged from R9) ----
  vgemm_f<<<dim3(2, 94), 256, 0, stream>>>(mic_f, WmT_f, nullptr, hbuf, 1500,
                                           128, 1500, 1500, 1500, 128);
  vgemm_f<<<dim3(2, 50), 256, 0, stream>>>(dis_f, WdT_f, nullptr,
                                           hbuf + (size_t)1500 * 128, 800, 128,
                                           800, 800, 800, 128);
  vgemm_f<<<dim3(16, 144), 256, 0, stream>>>(hbuf, WlT_f, bl_f, xlf, 2300,
                                             1024, 128, 128, 128, 1024);
  vgemm_f<<<dim3(16, 144), 256, 0, stream>>>(hbuf, WrT_f, br_f, xrf, 2300,
                                             1024, 128, 128, 128, 1024);

  k_edge_e<<<(ET + 3) / 4, 256, 0, stream>>>(xlf, xrf, ei, att_f, ebuf, E, ET);
  k_count<<<(ET + 255) / 256, 256, 0, stream>>>(ei, cnt, E, ET);
  k_scan<<<1, 256, 0, stream>>>(cnt, rowst, 2300);
  k_scatter<<<(ET + 255) / 256, 256, 0, stream>>>(ei, rowst, cur, csr, E, ET);
  k_softmax<<<(2300 + 3) / 4, 256, 0, stream>>>(ebuf, csr, rowst, wbuf, 2300, ET);
  k_aggregate<<<2300, 256, 0, stream>>>(wbuf, xlf, ei, csr, rowst, gbias_f,
                                        resf, E, ET);

  k_cnn<<<2300, 256, 0, stream>>>(resf, cw1_f, cb1_f, cw4_f, cb4_f, cw16_f,
                                  cb16_f, cw32_f, cb32_f, outc, emb);

  // ---- MLP: MFMA bf16, chunked; gather fused into L1 A-staging ----
  for (int c0 = 0; c0 < M; c0 += R) {
    int rows = (M - c0 < R) ? (M - c0) : R;
    int gby = (rows + 127) / 128;
    mgemm<1><<<dim3(11, gby), 256, 0, stream>>>(
        nullptr, m1T, mb1_b, hh1, rows, 1389, 2784, 2784, 2784, 1408, 0.01f,
        emb, posp, negp, P, c0);
    mgemm<0><<<dim3(6, gby), 256, 0, stream>>>(
        hh1, m2T, mb2_b, hh2, rows, 694, 1408, 1408, 1408, 704, 0.01f, nullptr,
        nullptr, nullptr, 0, 0);
    mgemm<0><<<dim3(4, gby), 256, 0, stream>>>(
        hh2, m3T, mb3_b, hh1, rows, 463, 704, 704, 704, 480, 0.01f, nullptr,
        nullptr, nullptr, 0, 0);
    k_gemv_sig<<<(rows + 3) / 4, 256, 0, stream>>>(hh1, mw4_b, outp + c0, rows,
                                                   463, 480);
  }
}

// Round 11
// 2720.733 us; speedup vs baseline: 13.1925x; 1.1729x over previous
//
#include <hip/hip_runtime.h>

// ===========================================================================
// GAT_CNN_DASE :: gfx950 :: R11.
// R10: 3191 us; L1 mgemm 1056 us (584 TF, VALUBusy 32% = gather/repack done
// 11x per element in A-staging, no async staging).
// R11: (1) k_feats precomputes pair-product chunk once (bf16, L3-resident,
// R<=16256); (2) all MLP GEMMs use global_load_lds width=16 staging (m97
// ladder step: LDS image byte t*16 == wave base + lane*16); (3) B weights
// zero-padded to tile-multiple rows (guard-free staging); (4) tiled-LDS
// transpose for MLP weight conversion. Front end unchanged.
// ===========================================================================

typedef unsigned short u16;
typedef __attribute__((ext_vector_type(8))) short bf16x8;
typedef __attribute__((ext_vector_type(4))) float f32x4;

__device__ __forceinline__ float b2f(u16 u) {
  unsigned v = ((unsigned)u) << 16;
  return __builtin_bit_cast(float, v);
}
__device__ __forceinline__ u16 f2b(float f) {
  unsigned x = __builtin_bit_cast(unsigned, f);
  x += 0x7fffu + ((x >> 16) & 1u);
  return (u16)(x >> 16);
}

// async global->LDS, 16B per lane; LDS dest = wave-uniform base + lane*16
__device__ __forceinline__ void async_ld16(const u16* g, u16* l) {
  __builtin_amdgcn_global_load_lds(
      (const __attribute__((address_space(1))) void*)g,
      (__attribute__((address_space(3))) void*)l, 16, 0, 0);
}

// bf16 data: ~100% of u16s have exponent in [100,140]; f32-as-u16: ~58%.
__device__ __forceinline__ int sniff_bf16(const void* p, int n) {
  const u16* pu = (const u16*)p;
  int ns = n < 128 ? n : 128;
  int sane = 0, nz = 0;
  for (int i = 0; i < ns; i++) {
    u16 v = pu[i];
    if (v) nz++;
    int e = (v >> 7) & 0xFF;
    if (e >= 100 && e <= 140) sane++;
  }
  return (nz == 0) || (sane * 8 >= ns * 7);
}
__device__ __forceinline__ float ld_any(const void* p, size_t i, int isbf) {
  return isbf ? b2f(((const u16*)p)[i]) : ((const float*)p)[i];
}

__global__ void cvt_f(const void* __restrict__ in, float* __restrict__ out,
                      int n) {
  __shared__ int sbf;
  if (threadIdx.x == 0) sbf = sniff_bf16(in, n);
  __syncthreads();
  int tid = blockIdx.x * 256 + threadIdx.x;
  if (tid < n) out[tid] = ld_any(in, tid, sbf);
}
// in[k*N+n] -> out[n*K+k] (small front-end weights)
__global__ void cvt_f_t(const void* __restrict__ in, float* __restrict__ out,
                        int K, int N) {
  __shared__ int sbf;
  if (threadIdx.x == 0) sbf = sniff_bf16(in, K * N);
  __syncthreads();
  int tid = blockIdx.x * 256 + threadIdx.x;
  if (tid >= K * N) return;
  int nn = tid / K, k = tid - nn * K;
  out[tid] = ld_any(in, (size_t)k * N + nn, sbf);
}
__global__ void cvt_b(const void* __restrict__ in, u16* __restrict__ out,
                      int n) {
  __shared__ int sbf;
  if (threadIdx.x == 0) sbf = sniff_bf16(in, n);
  __syncthreads();
  int tid = blockIdx.x * 256 + threadIdx.x;
  if (tid < n) out[tid] = f2b(ld_any(in, tid, sbf));
}
// tiled transpose-convert: in K x N -> out Npad x Kpad bf16, zero-padded.
__global__ void cvt_b_tt(const void* __restrict__ in, u16* __restrict__ out,
                         int K, int N, int Kpad, int Npad) {
  __shared__ int sbf;
  __shared__ float tile[32][33];
  if (threadIdx.x == 0) sbf = sniff_bf16(in, K * N);
  __syncthreads();
  int k0 = blockIdx.x * 32, n0 = blockIdx.y * 32;
  int tx = threadIdx.x & 31, ty = threadIdx.x >> 5;  // 32x8
#pragma unroll
  for (int i = 0; i < 32; i += 8) {
    int k = k0 + ty + i, n = n0 + tx;
    tile[ty + i][tx] =
        (k < K && n < N) ? ld_any(in, (size_t)k * N + n, sbf) : 0.f;
  }
  __syncthreads();
#pragma unroll
  for (int i = 0; i < 32; i += 8) {
    int n = n0 + ty + i, k = k0 + tx;
    if (n < Npad && k < Kpad) out[(size_t)n * Kpad + k] = f2b(tile[tx][ty + i]);
  }
}

// ---------------------------------------------------------------------------
// feats chunk: feats[r][0..2784) = emb[p0[mbase+r]] * emb[1500+p1[mbase+r]]
// (emb rows are 2784 wide, cols 2778.. zeroed). One thread per 8 elements.
// ---------------------------------------------------------------------------
__global__ void k_feats(const u16* __restrict__ emb,
                        const int* __restrict__ posp,
                        const int* __restrict__ negp, int npos, int mbase,
                        int rows, u16* __restrict__ feats) {
  int idx = blockIdx.x * 256 + threadIdx.x;
  int r = idx / 348, c8 = (idx - r * 348) * 8;
  if (r >= rows) return;
  int g = mbase + r;
  const int* pp = (g < npos) ? (posp + 2 * g) : (negp + 2 * (g - npos));
  bf16x8 x = *(const bf16x8*)(emb + (size_t)pp[0] * 2784 + c8);
  bf16x8 y = *(const bf16x8*)(emb + (size_t)(1500 + pp[1]) * 2784 + c8);
  bf16x8 v;
#pragma unroll
  for (int j = 0; j < 8; j++)
    ((u16*)&v)[j] = f2b(b2f((u16)x[j]) * b2f((u16)y[j]));
  *(bf16x8*)(feats + (size_t)r * 2784 + c8) = v;
}

// ---------------------------------------------------------------------------
// MFMA bf16 GEMM with global_load_lds staging. A: M x lda (rows padded to
// 128-mult, allocation-safe), BT: N-padded x ldb (tile-mult rows, zero pad).
// C = lrelu(A@B + bias); epilogue zero-fills cols [N, ldc).
// ---------------------------------------------------------------------------
__global__ __launch_bounds__(256, 2) void mgemm(
    const u16* __restrict__ A, const u16* __restrict__ BT,
    const u16* __restrict__ bias, u16* __restrict__ C, int M, int N, int Kpad,
    int lda, int ldb, int ldc, float slope) {
  __shared__ u16 As[128 * 32];
  __shared__ u16 Bs[128 * 32];
  const int t = threadIdx.x;
  const int lane = t & 63, wave = t >> 6;
  const int quad = lane >> 4, l16 = lane & 15;
  const int wm = wave >> 1, wn = wave & 1;
  const int m0 = blockIdx.y * 128, n0 = blockIdx.x * 128;

  const int r0 = t >> 2;       // staging row (byte addr == t*16)
  const int kc = (t & 3) * 8;  // k-chunk 0/8/16/24

  f32x4 zero4 = {0.f, 0.f, 0.f, 0.f};
  f32x4 acc[4][4];
#pragma unroll
  for (int i = 0; i < 4; i++)
#pragma unroll
    for (int j = 0; j < 4; j++) acc[i][j] = zero4;

  u16* As_w = &As[wave * 512];  // wave-uniform LDS bases
  u16* Bs_w = &Bs[wave * 512];
  const u16* Ap = A + (size_t)(m0 + r0) * lda + kc;
  const u16* Bp = BT + (size_t)(n0 + r0) * ldb + kc;
  const size_t a64 = (size_t)64 * lda, b64 = (size_t)64 * ldb;

  for (int k0 = 0; k0 < Kpad; k0 += 32) {
    async_ld16(Ap + k0, As_w);
    async_ld16(Ap + a64 + k0, As_w + 2048);
    async_ld16(Bp + k0, Bs_w);
    async_ld16(Bp + b64 + k0, Bs_w + 2048);
    __syncthreads();
    bf16x8 af[4], bfr[4];
#pragma unroll
    for (int i = 0; i < 4; i++)
      af[i] = *(const bf16x8*)(&As[(wm * 64 + i * 16 + l16) * 32 + quad * 8]);
#pragma unroll
    for (int j = 0; j < 4; j++)
      bfr[j] = *(const bf16x8*)(&Bs[(wn * 64 + j * 16 + l16) * 32 + quad * 8]);
#pragma unroll
    for (int i = 0; i < 4; i++)
#pragma unroll
      for (int j = 0; j < 4; j++)
        acc[i][j] = __builtin_amdgcn_mfma_f32_16x16x32_bf16(af[i], bfr[j],
                                                            acc[i][j], 0, 0, 0);
    __syncthreads();
  }

#pragma unroll
  for (int j = 0; j < 4; j++) {
    int col = n0 + wn * 64 + j * 16 + l16;
    if (col >= ldc) continue;
    float bv = 0.f;
    if (bias != nullptr && col < N) bv = b2f(bias[col]);
#pragma unroll
    for (int i = 0; i < 4; i++) {
#pragma unroll
      for (int r = 0; r < 4; r++) {
        int row = m0 + wm * 64 + i * 16 + quad * 4 + r;
        if (row >= M) continue;
        float v;
        if (col < N) {
          v = acc[i][j][r] + bv;
          v = (v > 0.f) ? v : v * slope;
        } else {
          v = 0.f;
        }
        C[(size_t)row * ldc + col] = f2b(v);
      }
    }
  }
}

// ---------------------------------------------------------------------------
// f32 VALU GEMM (front end)
// ---------------------------------------------------------------------------
__global__ __launch_bounds__(256) void vgemm_f(
    const float* __restrict__ A, const float* __restrict__ BT,
    const float* __restrict__ bias, float* __restrict__ C, int M, int N, int K,
    int lda, int ldb, int ldc) {
  __shared__ float As[16 * 66];
  __shared__ float Bs[64 * 66];
  const int t = threadIdx.x;
  const int m0 = blockIdx.y * 16, n0 = blockIdx.x * 64;
  const int tx = t & 63, ty = t >> 6;
  float acc[4] = {0.f, 0.f, 0.f, 0.f};
  for (int k0 = 0; k0 < K; k0 += 64) {
    for (int idx = t; idx < 16 * 64; idx += 256) {
      int r = idx >> 6, k = idx & 63;
      int m = m0 + r, kk = k0 + k;
      As[r * 66 + k] = (m < M && kk < K) ? A[(size_t)m * lda + kk] : 0.f;
    }
    for (int idx = t; idx < 64 * 64; idx += 256) {
      int nr = idx >> 6, k = idx & 63;
      int nn = n0 + nr, kk = k0 + k;
      Bs[nr * 66 + k] = (nn < N && kk < K) ? BT[(size_t)nn * ldb + kk] : 0.f;
    }
    __syncthreads();
#pragma unroll 8
    for (int k = 0; k < 64; k++) {
      float b = Bs[tx * 66 + k];
#pragma unroll
      for (int q = 0; q < 4; q++) acc[q] += As[(ty * 4 + q) * 66 + k] * b;
    }
    __syncthreads();
  }
  int col = n0 + tx;
  if (col >= N) return;
  float bv = (bias != nullptr) ? bias[col] : 0.f;
#pragma unroll
  for (int q = 0; q < 4; q++) {
    int row = m0 + ty * 4 + q;
    if (row < M) C[(size_t)row * ldc + col] = acc[q] + bv;
  }
}

__global__ void k_zero2(int* __restrict__ a, int* __restrict__ b, int n) {
  int tid = blockIdx.x * 256 + threadIdx.x;
  if (tid < n) { a[tid] = 0; b[tid] = 0; }
}

// ---------------------------------------------------------------------------
// GAT
// ---------------------------------------------------------------------------
__global__ void k_edge_e(const float* __restrict__ xl,
                         const float* __restrict__ xr,
                         const int* __restrict__ ei,
                         const float* __restrict__ att, float* __restrict__ e,
                         int E, int Etot) {
  __shared__ float attf[1024];
  int t = threadIdx.x;
  for (int i = t; i < 1024; i += 256) attf[i] = att[i];
  __syncthreads();
  int lane = t & 63;
  int eid = blockIdx.x * 4 + (t >> 6);
  if (eid >= Etot) return;
  int src = (eid < E) ? ei[eid] : (eid - E);
  int dst = (eid < E) ? ei[E + eid] : (eid - E);
  const float* pl = xl + (size_t)src * 1024;
  const float* pr = xr + (size_t)dst * 1024;
#pragma unroll
  for (int h = 0; h < 8; h++) {
    float a0 = pl[h * 128 + lane] + pr[h * 128 + lane];
    float a1 = pl[h * 128 + 64 + lane] + pr[h * 128 + 64 + lane];
    a0 = (a0 > 0.f) ? a0 : 0.2f * a0;
    a1 = (a1 > 0.f) ? a1 : 0.2f * a1;
    float p = a0 * attf[h * 128 + lane] + a1 * attf[h * 128 + 64 + lane];
#pragma unroll
    for (int off = 32; off; off >>= 1) p += __shfl_xor(p, off);
    if (lane == 0) e[(size_t)eid * 8 + h] = p;
  }
}

__global__ void k_count(const int* __restrict__ ei, int* __restrict__ cnt,
                        int E, int Etot) {
  int tid = blockIdx.x * 256 + threadIdx.x;
  if (tid >= Etot) return;
  int dst = (tid < E) ? ei[E + tid] : (tid - E);
  atomicAdd(&cnt[dst], 1);
}

__global__ void k_scan(const int* __restrict__ cnt, int* __restrict__ rowstart,
                       int Nn) {
  __shared__ int part[257];
  int t = threadIdx.x;
  int chunk = (Nn + 255) / 256;
  int b = t * chunk;
  int en = b + chunk; if (en > Nn) en = Nn;
  int s = 0;
  for (int i = b; i < en; i++) s += cnt[i];
  part[t] = s;
  __syncthreads();
  if (t == 0) {
    int acc = 0;
    for (int i = 0; i < 256; i++) { int v = part[i]; part[i] = acc; acc += v; }
    part[256] = acc;
  }
  __syncthreads();
  int run = part[t];
  for (int i = b; i < en; i++) { rowstart[i] = run; run += cnt[i]; }
  if (t == 0) rowstart[Nn] = part[256];
}

__global__ void k_scatter(const int* __restrict__ ei,
                          const int* __restrict__ rowstart,
                          int* __restrict__ cur, int* __restrict__ csr, int E,
                          int Etot) {
  int tid = blockIdx.x * 256 + threadIdx.x;
  if (tid >= Etot) return;
  int dst = (tid < E) ? ei[E + tid] : (tid - E);
  int p = atomicAdd(&cur[dst], 1);
  unsigned idx = (unsigned)(rowstart[dst] + p);
  if (idx < (unsigned)Etot) csr[idx] = tid;
}

__global__ void k_softmax(const float* __restrict__ e,
                          const int* __restrict__ csr,
                          const int* __restrict__ rowstart,
                          float* __restrict__ wgt, int Nn, int Etot) {
  int t = threadIdx.x;
  int lane = t & 63;
  int d = blockIdx.x * 4 + (t >> 6);
  if (d >= Nn) return;
  int rs = rowstart[d], re = rowstart[d + 1];
  for (int h = 0; h < 8; h++) {
    float mx = -3.0e38f;
    for (int i = rs + lane; i < re; i += 64) {
      unsigned eid = (unsigned)csr[i];
      if (eid < (unsigned)Etot) mx = fmaxf(mx, e[(size_t)eid * 8 + h]);
    }
#pragma unroll
    for (int off = 32; off; off >>= 1) mx = fmaxf(mx, __shfl_xor(mx, off));
    if (mx < -1.0e37f) mx = 0.f;
    float s = 0.f;
    for (int i = rs + lane; i < re; i += 64) {
      unsigned eid = (unsigned)csr[i];
      if (eid < (unsigned)Etot) s += expf(e[(size_t)eid * 8 + h] - mx);
    }
#pragma unroll
    for (int off = 32; off; off >>= 1) s += __shfl_xor(s, off);
    float inv = (s > 0.f) ? 1.f / s : 0.f;
    for (int i = rs + lane; i < re; i += 64) {
      unsigned eid = (unsigned)csr[i];
      if (eid < (unsigned)Etot)
        wgt[(size_t)eid * 8 + h] = expf(e[(size_t)eid * 8 + h] - mx) * inv;
    }
  }
}

__global__ void k_aggregate(const float* __restrict__ wgt,
                            const float* __restrict__ xl,
                            const int* __restrict__ ei,
                            const int* __restrict__ csr,
                            const int* __restrict__ rowstart,
                            const float* __restrict__ gbias,
                            float* __restrict__ res, int E, int Etot) {
  int d = blockIdx.x;
  int t = threadIdx.x;
  int c = t & 127, hb = t >> 7;
  int rs = rowstart[d], re = rowstart[d + 1];
  float acc[4] = {0.f, 0.f, 0.f, 0.f};
  for (int i = rs; i < re; i++) {
    unsigned eid = (unsigned)csr[i];
    if (eid >= (unsigned)Etot) continue;
    int src = (eid < (unsigned)E) ? ei[eid] : (int)(eid - E);
    const float* px = xl + (size_t)src * 1024 + hb * 512 + c;
    const float* pw = wgt + (size_t)eid * 8 + hb * 4;
#pragma unroll
    for (int q = 0; q < 4; q++) acc[q] += pw[q] * px[q * 128];
  }
#pragma unroll
  for (int q = 0; q < 4; q++) {
    int idx = (hb * 4 + q) * 128 + c;
    res[(size_t)d * 1024 + idx] = acc[q] + gbias[idx];
  }
}

// ---------------------------------------------------------------------------
// CNN: f32 in, f32 out to d_out (stride 2778), bf16 emb (stride 2784, padded)
// ---------------------------------------------------------------------------
__global__ void k_cnn(const float* __restrict__ res,
                      const float* __restrict__ cw1, const float* __restrict__ cb1,
                      const float* __restrict__ cw4, const float* __restrict__ cb4,
                      const float* __restrict__ cw16, const float* __restrict__ cb16,
                      const float* __restrict__ cw32, const float* __restrict__ cb32,
                      float* __restrict__ outc, u16* __restrict__ emb) {
  __shared__ float xs[1024];
  __shared__ float wc[2544];
  __shared__ float cb[24];
  int t = threadIdx.x, node = blockIdx.x;
  for (int i = t; i < 1024; i += 256) xs[i] = res[(size_t)node * 1024 + i];
  for (int i = t; i < 48; i += 256) wc[i] = cw1[i];
  for (int i = t; i < 192; i += 256) wc[48 + i] = cw4[i];
  for (int i = t; i < 768; i += 256) wc[240 + i] = cw16[i];
  for (int i = t; i < 1536; i += 256) wc[1008 + i] = cw32[i];
  if (t < 6) {
    cb[t] = cb1[t];
    cb[6 + t] = cb4[t];
    cb[12 + t] = cb16[t];
    cb[18 + t] = cb32[t];
  }
  __syncthreads();
  for (int o = t; o < 2778; o += 256) {
    int k, W, base, boff, rr;
    if (o < 768)       { k = 1;  W = 128; base = 0;    boff = 0;  rr = o; }
    else if (o < 1518) { k = 4;  W = 125; base = 48;   boff = 6;  rr = o - 768; }
    else if (o < 2196) { k = 16; W = 113; base = 240;  boff = 12; rr = o - 1518; }
    else               { k = 32; W = 97;  base = 1008; boff = 18; rr = o - 2196; }
    int oc = rr / W, wp = rr - oc * W;
    const float* wgt = &wc[base + oc * 8 * k];
    float v = cb[boff + oc];
    for (int h = 0; h < 8; h++)
      for (int j = 0; j < k; j++) v += xs[h * 128 + wp + j] * wgt[h * k + j];
    v = fmaxf(v, 0.f);
    outc[(size_t)node * 2778 + o] = v;
    emb[(size_t)node * 2784 + o] = f2b(v);
  }
  if (t < 6) emb[(size_t)node * 2784 + 2778 + t] = 0;  // zero K-pad
}

// ---------------------------------------------------------------------------
__global__ void k_gemv_sig(const u16* __restrict__ hh3,
                           const u16* __restrict__ w4, float* __restrict__ pred,
                           int M, int K, int ldk) {
  __shared__ float ws[464];
  int t = threadIdx.x;
  for (int i = t; i < K; i += 256) ws[i] = b2f(w4[i]);
  __syncthreads();
  int lane = t & 63;
  int m = blockIdx.x * 4 + (t >> 6);
  if (m >= M) return;
  const u16* p = hh3 + (size_t)m * ldk;
  float s = 0.f;
  for (int i = lane; i < K; i += 64) s += b2f(p[i]) * ws[i];
#pragma unroll
  for (int off = 32; off; off >>= 1) s += __shfl_xor(s, off);
  if (!(s == s)) s = 0.f;
  s = fminf(fmaxf(s, -30.f), 30.f);
  if (lane == 0) pred[m] = 1.f / (1.f + expf(-s));
}

__global__ void k_labels(float* __restrict__ lab, int P) {
  int tid = blockIdx.x * 256 + threadIdx.x;
  if (tid < 2 * P) lab[tid] = (tid < P) ? 1.f : 0.f;
}

__global__ void k_sentinel(float* __restrict__ pred, int M, float val) {
  int tid = blockIdx.x * 256 + threadIdx.x;
  if (tid < M) pred[tid] = val;
}

// ---------------------------------------------------------------------------
extern "C" void kernel_launch(void* const* d_in, const int* in_sizes, int n_in,
                              void* d_out, int out_size, void* d_ws,
                              size_t ws_size, hipStream_t stream) {
  (void)in_sizes; (void)n_in; (void)out_size;
  const int* ei = (const int*)d_in[2];
  const int* posp = (const int*)d_in[3];
  const int* negp = (const int*)d_in[4];

  const int E = 80000, ET = 82300, P = 40000, M = 80000;

  float* outp = (float*)d_out;
  float* outl = outp + 80000;
  float* outc = outp + 160000;

  k_labels<<<(2 * P + 255) / 256, 256, 0, stream>>>(outl, P);

  char* base = (char*)d_ws;
  size_t off = 0;
  auto alloc = [&](size_t bytes) -> void* {
    void* p = base + off;
    off = (off + bytes + 255) & ~(size_t)255;
    return p;
  };
  // front-end f32 copies
  float* mic_f = (float*)alloc((size_t)1500 * 1500 * 4);
  float* dis_f = (float*)alloc((size_t)800 * 800 * 4);
  float* WmT_f = (float*)alloc((size_t)128 * 1500 * 4);
  float* WdT_f = (float*)alloc((size_t)128 * 800 * 4);
  float* WlT_f = (float*)alloc((size_t)1024 * 128 * 4);
  float* WrT_f = (float*)alloc((size_t)1024 * 128 * 4);
  float* bl_f = (float*)alloc(1024 * 4);
  float* br_f = (float*)alloc(1024 * 4);
  float* att_f = (float*)alloc(1024 * 4);
  float* gbias_f = (float*)alloc(1024 * 4);
  float* cw1_f = (float*)alloc(48 * 4);
  float* cb1_f = (float*)alloc(6 * 4);
  float* cw4_f = (float*)alloc(192 * 4);
  float* cb4_f = (float*)alloc(6 * 4);
  float* cw16_f = (float*)alloc(768 * 4);
  float* cb16_f = (float*)alloc(6 * 4);
  float* cw32_f = (float*)alloc(1536 * 4);
  float* cb32_f = (float*)alloc(6 * 4);
  // MLP bf16 weights: rows padded to tile multiple, K padded, zero-filled
  u16* m1T = (u16*)alloc((size_t)1408 * 2784 * 2);  // N 1389->1408, K 2778->2784
  u16* m2T = (u16*)alloc((size_t)768 * 1408 * 2);   // N 694->768,  K 1389->1408
  u16* m3T = (u16*)alloc((size_t)512 * 704 * 2);    // N 463->512,  K 694->704
  u16* mb1_b = (u16*)alloc(1389 * 2);
  u16* mb2_b = (u16*)alloc(694 * 2);
  u16* mb3_b = (u16*)alloc(463 * 2);
  u16* mw4_b = (u16*)alloc(463 * 2);
  // intermediates
  float* hbuf = (float*)alloc((size_t)2300 * 128 * 4);
  float* xlf = (float*)alloc((size_t)2300 * 1024 * 4);
  float* xrf = (float*)alloc((size_t)2300 * 1024 * 4);
  float* resf = xrf;  // xr dead after k_edge_e
  float* ebuf = (float*)alloc((size_t)ET * 8 * 4);
  float* wbuf = (float*)alloc((size_t)ET * 8 * 4);
  u16* emb = (u16*)alloc((size_t)2300 * 2784 * 2);
  int* cnt = (int*)alloc(2300 * 4);
  int* rowst = (int*)alloc(2304 * 4);
  int* cur = (int*)alloc(2300 * 4);
  int* csr = (int*)alloc((size_t)ET * 4);
  size_t fixed_end = off;

  // chunk: feats (R x 2784) + hh1 (R x 1408) + hh2 (R x 704), bf16
  const size_t per_row = (size_t)(2784 + 1408 + 704) * 2;
  size_t avail = (ws_size > fixed_end) ? (ws_size - fixed_end) : 0;
  long long Rll = (long long)(avail / per_row);
  int R = (Rll > M) ? M : (int)Rll;
  R &= ~127;
  if (R > 16256) R = 16256;  // keep feats chunk (~90MB) L3-resident
  if (fixed_end > ws_size || R < 128) {
    k_sentinel<<<(M + 255) / 256, 256, 0, stream>>>(outp, M, 0.25f);
    return;
  }
  u16* feats = (u16*)(base + fixed_end);
  u16* hh1 = feats + (size_t)R * 2784;
  u16* hh2 = hh1 + (size_t)R * 1408;

  k_zero2<<<(2300 + 255) / 256, 256, 0, stream>>>(cnt, cur, 2300);

  // ---- canonicalize inputs ----
  cvt_f<<<(2250000 + 255) / 256, 256, 0, stream>>>(d_in[0], mic_f, 2250000);
  cvt_f<<<(640000 + 255) / 256, 256, 0, stream>>>(d_in[1], dis_f, 640000);
  cvt_f_t<<<(192000 + 255) / 256, 256, 0, stream>>>(d_in[6], WmT_f, 1500, 128);
  cvt_f_t<<<(102400 + 255) / 256, 256, 0, stream>>>(d_in[7], WdT_f, 800, 128);
  cvt_f_t<<<(131072 + 255) / 256, 256, 0, stream>>>(d_in[8], WlT_f, 128, 1024);
  cvt_f<<<4, 256, 0, stream>>>(d_in[9], bl_f, 1024);
  cvt_f_t<<<(131072 + 255) / 256, 256, 0, stream>>>(d_in[10], WrT_f, 128, 1024);
  cvt_f<<<4, 256, 0, stream>>>(d_in[11], br_f, 1024);
  cvt_f<<<4, 256, 0, stream>>>(d_in[12], att_f, 1024);
  cvt_f<<<4, 256, 0, stream>>>(d_in[13], gbias_f, 1024);
  cvt_f<<<1, 256, 0, stream>>>(d_in[14], cw1_f, 48);
  cvt_f<<<1, 256, 0, stream>>>(d_in[15], cb1_f, 6);
  cvt_f<<<1, 256, 0, stream>>>(d_in[16], cw4_f, 192);
  cvt_f<<<1, 256, 0, stream>>>(d_in[17], cb4_f, 6);
  cvt_f<<<3, 256, 0, stream>>>(d_in[18], cw16_f, 768);
  cvt_f<<<1, 256, 0, stream>>>(d_in[19], cb16_f, 6);
  cvt_f<<<6, 256, 0, stream>>>(d_in[20], cw32_f, 1536);
  cvt_f<<<1, 256, 0, stream>>>(d_in[21], cb32_f, 6);
  cvt_b_tt<<<dim3((2784 + 31) / 32, (1408 + 31) / 32), 256, 0, stream>>>(
      d_in[22], m1T, 2778, 1389, 2784, 1408);
  cvt_b<<<(1389 + 255) / 256, 256, 0, stream>>>(d_in[23], mb1_b, 1389);
  cvt_b_tt<<<dim3((1408 + 31) / 32, (768 + 31) / 32), 256, 0, stream>>>(
      d_in[24], m2T, 1389, 694, 1408, 768);
  cvt_b<<<(694 + 255) / 256, 256, 0, stream>>>(d_in[25], mb2_b, 694);
  cvt_b_tt<<<dim3((704 + 31) / 32, (512 + 31) / 32), 256, 0, stream>>>(
      d_in[26], m3T, 694, 463, 704, 512);
  cvt_b<<<(463 + 255) / 256, 256, 0, stream>>>(d_in[27], mb3_b, 463);
  cvt_b<<<(463 + 255) / 256, 256, 0, stream>>>(d_in[28], mw4_b, 463);

  // ---- front end ----
  vgemm_f<<<dim3(2, 94), 256, 0, stream>>>(mic_f, WmT_f, nullptr, hbuf, 1500,
                                           128, 1500, 1500, 1500, 128);
  vgemm_f<<<dim3(2, 50), 256, 0, stream>>>(dis_f, WdT_f, nullptr,
                                           hbuf + (size_t)1500 * 128, 800, 128,
                                           800, 800, 800, 128);
  vgemm_f<<<dim3(16, 144), 256, 0, stream>>>(hbuf, WlT_f, bl_f, xlf, 2300,
                                             1024, 128, 128, 128, 1024);
  vgemm_f<<<dim3(16, 144), 256, 0, stream>>>(hbuf, WrT_f, br_f, xrf, 2300,
                                             1024, 128, 128, 128, 1024);

  k_edge_e<<<(ET + 3) / 4, 256, 0, stream>>>(xlf, xrf, ei, att_f, ebuf, E, ET);
  k_count<<<(ET + 255) / 256, 256, 0, stream>>>(ei, cnt, E, ET);
  k_scan<<<1, 256, 0, stream>>>(cnt, rowst, 2300);
  k_scatter<<<(ET + 255) / 256, 256, 0, stream>>>(ei, rowst, cur, csr, E, ET);
  k_softmax<<<(2300 + 3) / 4, 256, 0, stream>>>(ebuf, csr, rowst, wbuf, 2300, ET);
  k_aggregate<<<2300, 256, 0, stream>>>(wbuf, xlf, ei, csr, rowst, gbias_f,
                                        resf, E, ET);

  k_cnn<<<2300, 256, 0, stream>>>(resf, cw1_f, cb1_f, cw4_f, cb4_f, cw16_f,
                                  cb16_f, cw32_f, cb32_f, outc, emb);

  // ---- MLP: feats precompute + MFMA (global_load_lds staging), chunked ----
  for (int c0 = 0; c0 < M; c0 += R) {
    int rows = (M - c0 < R) ? (M - c0) : R;
    int gby = (rows + 127) / 128;
    k_feats<<<((size_t)rows * 348 + 255) / 256, 256, 0, stream>>>(
        emb, posp, negp, P, c0, rows, feats);
    mgemm<<<dim3(11, gby), 256, 0, stream>>>(feats, m1T, mb1_b, hh1, rows,
                                             1389, 2784, 2784, 2784, 1408,
                                             0.01f);
    mgemm<<<dim3(6, gby), 256, 0, stream>>>(hh1, m2T, mb2_b, hh2, rows, 694,
                                            1408, 1408, 1408, 704, 0.01f);
    mgemm<<<dim3(4, gby), 256, 0, stream>>>(hh2, m3T, mb3_b, hh1, rows, 463,
                                            704, 704, 704, 480, 0.01f);
    k_gemv_sig<<<(rows + 3) / 4, 256, 0, stream>>>(hh1, mw4_b, outp + c0, rows,
                                                   463, 480);
  }
}